// Round 7
// baseline (226.380 us; speedup 1.0000x reference)
//
#include <hip/hip_runtime.h>

// Problem constants (reference: N=16, A=2048, B=2048, H=64)
#define NB 16
#define AQ 2048
#define BKV 2048
#define HD 64

#define MROW 68  // padded f32 row for merge buffer
#define L2E 1.44269504f

typedef float f32x4 __attribute__((ext_vector_type(4)));
typedef short bf16x8 __attribute__((ext_vector_type(8)));
typedef short short4v __attribute__((ext_vector_type(4)));
typedef int int4v __attribute__((ext_vector_type(4)));

__device__ __forceinline__ short f2bf(float f) {
  return __builtin_bit_cast(short, static_cast<__bf16>(f));
}

// -------------------- fused prepass (single launch) --------------------------
// blocks [0, 1024):   K f32 [n][b][h] -> Kb bf16 [n][b][h]
// blocks [1024, 1536): V f32 [n][b][h] -> Vt bf16 [n][h][b]  (64x64 LDS tile)
__global__ __launch_bounds__(256) void prepack(const float* __restrict__ K,
                                               const float* __restrict__ V,
                                               short* __restrict__ Kb,
                                               short* __restrict__ Vt) {
  if (blockIdx.x < 1024) {
    size_t base = ((size_t)blockIdx.x * 256 + threadIdx.x) * 8;
    f32x4 a = *(const f32x4*)(K + base);
    f32x4 b = *(const f32x4*)(K + base + 4);
    bf16x8 o;
#pragma unroll
    for (int i = 0; i < 4; ++i) {
      o[i] = f2bf(a[i]);
      o[i + 4] = f2bf(b[i]);
    }
    *(bf16x8*)(Kb + base) = o;
  } else {
    unsigned vb = blockIdx.x - 1024;
    int n = vb >> 5;
    int b0 = (vb & 31) * 64;
    int t = threadIdx.x;
    __shared__ short tile[64][68];
    int rb = t >> 4;
    int hc = (t & 15) * 4;
#pragma unroll
    for (int j = 0; j < 4; ++j) {
      int r = rb + 16 * j;
      f32x4 v = *(const f32x4*)(V + ((size_t)n * BKV + b0 + r) * HD + hc);
#pragma unroll
      for (int i = 0; i < 4; ++i) tile[r][hc + i] = f2bf(v[i]);
    }
    __syncthreads();
    int hr = t >> 2;
    int bb = (t & 3) * 16;
    bf16x8 o0, o1;
#pragma unroll
    for (int j = 0; j < 8; ++j) {
      o0[j] = tile[bb + j][hr];
      o1[j] = tile[bb + 8 + j][hr];
    }
    short* dst = Vt + ((size_t)n * HD + hr) * BKV + b0 + bb;
    *(bf16x8*)dst = o0;
    *(bf16x8*)(dst + 8) = o1;
  }
}

// ---------------------------- main flash kernel ------------------------------
// Swapped-QK^T, in-block split-KV, 2 independent softmax states per wave (ILP).
// Block = 4 waves sharing 16 q rows. Each wave owns a 512-wide KV quarter,
// processed as TWO interleaved 256-wide eighths with private (m,l,acc,P-lds)
// state — two independent dependency chains per wave to hide latency
// (round-6 post-mortem: latency-bound, dur*occupancy ~ const, SIMDs 70% idle).
// States merge in-register, then 4-way block merge through LDS.
// __launch_bounds__(256, 4): VGPR cap 128. DO NOT raise min-waves to 8 —
// 64-VGPR cap spills acc to scratch (round-5: WRITE_SIZE 114-198 MB).
template <int PRE>
__global__ __launch_bounds__(256, 4) void attn_fwd(
    const float* __restrict__ Q, const float* __restrict__ K,
    const float* __restrict__ V, const int* __restrict__ M,
    const short* __restrict__ Kb, const short* __restrict__ Vt,
    float* __restrict__ O) {
  // bijective XCD swizzle: nwg=2048, 256 contiguous wgs per XCD (2 batches/XCD)
  unsigned orig = blockIdx.x;
  unsigned wg = (orig & 7u) * 256u + (orig >> 3);
  int n = (int)(wg >> 7);
  int q0 = (int)(wg & 127u) * 16;

  int w = threadIdx.x >> 6;
  int lane = threadIdx.x & 63;
  int g = lane >> 4;
  int c = lane & 15;

  const float* Qn = Q + (size_t)n * AQ * HD;
  const float* Kn = K + (size_t)n * BKV * HD;
  const float* Vn = V + (size_t)n * BKV * HD;
  const short* Kbn = Kb + (size_t)n * BKV * HD;
  const short* Vtn = Vt + (size_t)n * HD * BKV;
  const int* Mn = M + (size_t)n * BKV;

  // P staging: [4 waves][2 states][16 q][72 bf16] = 18432 B. The merge buffer
  // (17408 B f32) overlays the same memory; the post-loop __syncthreads() is
  // LOAD-BEARING (round-2 NaN post-mortem: cross-wave overlay race).
  __shared__ __align__(16) char rawsm[4 * 2 * 16 * 72 * 2];
  __shared__ float Ml[4][2][16];
  short* P0 = (short*)rawsm + (size_t)(w * 2 + 0) * (16 * 72);
  short* P1 = (short*)rawsm + (size_t)(w * 2 + 1) * (16 * 72);
  float* msm = (float*)rawsm;

  // Q fragments (B operand), scale 1/8 folded in.
  bf16x8 qb[2];
#pragma unroll
  for (int ks = 0; ks < 2; ++ks) {
    const float* qp = Qn + (size_t)(q0 + c) * HD + 32 * ks + 8 * g;
    f32x4 v0 = *(const f32x4*)qp;
    f32x4 v1 = *(const f32x4*)(qp + 4);
#pragma unroll
    for (int i = 0; i < 4; ++i) {
      qb[ks][i] = f2bf(v0[i] * 0.125f);
      qb[ks][i + 4] = f2bf(v1[i] * 0.125f);
    }
  }

  f32x4 acc2[2][4] = {};
  float mr2[2] = {-1e30f, -1e30f};
  float lr2[2] = {0.f, 0.f};

  const int bbeg = w * (BKV / 4);

  for (int it = 0; it < 4; ++it) {
    const int b0s[2] = {bbeg + it * 64, bbeg + 256 + it * 64};
    f32x4 st2[2][4];

    // ---- K loads + QK^T MFMAs, both states (independent chains)
#pragma unroll
    for (int s = 0; s < 2; ++s) {
      const int b0 = b0s[s];
#pragma unroll
      for (int t = 0; t < 4; ++t) {
        f32x4 z = {0.f, 0.f, 0.f, 0.f};
#pragma unroll
        for (int ks = 0; ks < 2; ++ks) {
          bf16x8 ka;
          if constexpr (PRE) {
            ka = *(const bf16x8*)(Kbn + (size_t)(b0 + 16 * t + c) * HD + 32 * ks + 8 * g);
          } else {
            const float* kp = Kn + (size_t)(b0 + 16 * t + c) * HD + 32 * ks + 8 * g;
            f32x4 k0 = *(const f32x4*)kp;
            f32x4 k1 = *(const f32x4*)(kp + 4);
#pragma unroll
            for (int i = 0; i < 4; ++i) {
              ka[i] = f2bf(k0[i]);
              ka[i + 4] = f2bf(k1[i]);
            }
          }
          z = __builtin_amdgcn_mfma_f32_16x16x32_bf16(ka, qb[ks], z, 0, 0, 0);
        }
        st2[s][t] = z;
      }
    }

    // ---- mask + tile row-max (in place), both states
    float mt2[2] = {-1e30f, -1e30f};
#pragma unroll
    for (int s = 0; s < 2; ++s) {
#pragma unroll
      for (int t = 0; t < 4; ++t) {
        int4v mv = *(const int4v*)(Mn + b0s[s] + 16 * t + 4 * g);
#pragma unroll
        for (int r = 0; r < 4; ++r) {
          float x = mv[r] ? -1e30f : st2[s][t][r];
          st2[s][t][r] = x;
          mt2[s] = fmaxf(mt2[s], x);
        }
      }
    }
#pragma unroll
    for (int s = 0; s < 2; ++s) {
      mt2[s] = fmaxf(mt2[s], __shfl_xor(mt2[s], 16));
      mt2[s] = fmaxf(mt2[s], __shfl_xor(mt2[s], 32));
    }

    // ---- P = exp(S - m) in place + row sums, both states
    float fac2[2], rs2[2];
#pragma unroll
    for (int s = 0; s < 2; ++s) {
      float mn = fmaxf(mr2[s], mt2[s]);
      fac2[s] = exp2f((mr2[s] - mn) * L2E);
      float rs = 0.f;
#pragma unroll
      for (int t = 0; t < 4; ++t) {
#pragma unroll
        for (int r = 0; r < 4; ++r) {
          float x = st2[s][t][r];
          float e = (x <= -1e29f) ? 0.f : exp2f((x - mn) * L2E);
          st2[s][t][r] = e;
          rs += e;
        }
      }
      rs2[s] = rs;
      mr2[s] = mn;
    }
#pragma unroll
    for (int s = 0; s < 2; ++s) {
      float rs = rs2[s];
      rs += __shfl_xor(rs, 16);
      rs += __shfl_xor(rs, 32);
      lr2[s] = lr2[s] * fac2[s] + rs;
    }

    // ---- rescale accumulator rows, both states
#pragma unroll
    for (int s = 0; s < 2; ++s) {
#pragma unroll
      for (int r = 0; r < 4; ++r) {
        float fr = __shfl(fac2[s], 4 * g + r);
#pragma unroll
        for (int th = 0; th < 4; ++th) acc2[s][th][r] *= fr;
      }
    }

    // ---- P -> wave-private LDS (per-state buffer, stride 72 shorts)
#pragma unroll
    for (int s = 0; s < 2; ++s) {
      short* P = (s == 0) ? P0 : P1;
#pragma unroll
      for (int t = 0; t < 4; ++t) {
        short4v pk;
#pragma unroll
        for (int r = 0; r < 4; ++r) pk[r] = f2bf(st2[s][t][r]);
        *(short4v*)(P + c * 72 + 16 * t + 4 * g) = pk;
      }
    }

    // ---- PV MFMAs, both states
#pragma unroll
    for (int s = 0; s < 2; ++s) {
      short* P = (s == 0) ? P0 : P1;
      bf16x8 pa[2];
#pragma unroll
      for (int ks = 0; ks < 2; ++ks)
        pa[ks] = *(const bf16x8*)(P + c * 72 + 32 * ks + 8 * g);
#pragma unroll
      for (int th = 0; th < 4; ++th) {
#pragma unroll
        for (int ks = 0; ks < 2; ++ks) {
          bf16x8 vb;
          if constexpr (PRE) {
            vb = *(const bf16x8*)(Vtn + (size_t)(16 * th + c) * BKV + b0s[s] + 32 * ks + 8 * g);
          } else {
            const float* vp = Vn + (size_t)(b0s[s] + 32 * ks + 8 * g) * HD + 16 * th + c;
#pragma unroll
            for (int i = 0; i < 8; ++i) vb[i] = f2bf(vp[(size_t)i * HD]);
          }
          acc2[s][th] = __builtin_amdgcn_mfma_f32_16x16x32_bf16(pa[ks], vb, acc2[s][th], 0, 0, 0);
        }
      }
    }
  }

  // ---- combine the wave's two states in-register
  float mm = fmaxf(mr2[0], mr2[1]);
  float f0 = exp2f((mr2[0] - mm) * L2E);
  float f1 = exp2f((mr2[1] - mm) * L2E);
  float ll = lr2[0] * f0 + lr2[1] * f1;
  f32x4 acc[4];
#pragma unroll
  for (int r = 0; r < 4; ++r) {
    float fr0 = __shfl(f0, 4 * g + r);
    float fr1 = __shfl(f1, 4 * g + r);
#pragma unroll
    for (int th = 0; th < 4; ++th)
      acc[th][r] = acc2[0][th][r] * fr0 + acc2[1][th][r] * fr1;
  }

  // ---- LOAD-BEARING barrier: P-staging reads must finish before the merge
  // buffer (which overlaps other waves' staging) is written.
  __syncthreads();

  if (g == 0) {
    Ml[w][0][c] = mm;
    Ml[w][1][c] = ll;
  }
#pragma unroll
  for (int r = 0; r < 4; ++r) {
#pragma unroll
    for (int th = 0; th < 4; ++th) {
      msm[(size_t)(w * 16 + 4 * g + r) * MROW + 16 * th + c] = acc[th][r];
    }
  }
  __syncthreads();

  // ---- merge 4 wave-partials; 256 threads cover 16 q x 16 h-quads
  {
    int tid = threadIdx.x;
    int q = tid >> 4;
    int hb = (tid & 15) * 4;
    float m0 = Ml[0][0][q], m1 = Ml[1][0][q];
    float m2 = Ml[2][0][q], m3 = Ml[3][0][q];
    float mmax = fmaxf(fmaxf(m0, m1), fmaxf(m2, m3));
    float lsum = 0.f;
    f32x4 o = {0.f, 0.f, 0.f, 0.f};
#pragma unroll
    for (int ww = 0; ww < 4; ++ww) {
      float f = exp2f((Ml[ww][0][q] - mmax) * L2E);
      lsum += f * Ml[ww][1][q];
      f32x4 a = *(const f32x4*)(msm + (size_t)(ww * 16 + q) * MROW + hb);
#pragma unroll
      for (int i = 0; i < 4; ++i) o[i] += f * a[i];
    }
    float inv = 1.0f / lsum;
    f32x4 res;
#pragma unroll
    for (int i = 0; i < 4; ++i) res[i] = o[i] * inv;
    *(f32x4*)(O + ((size_t)n * AQ + q0 + q) * HD + hb) = res;
  }
}

extern "C" void kernel_launch(void* const* d_in, const int* in_sizes, int n_in,
                              void* d_out, int out_size, void* d_ws, size_t ws_size,
                              hipStream_t stream) {
  const float* q = (const float*)d_in[0];
  const float* k = (const float*)d_in[1];
  const float* v = (const float*)d_in[2];
  const int* m = (const int*)d_in[3];
  float* o = (float*)d_out;

  const size_t kv_elems = (size_t)NB * BKV * HD;     // 2,097,152
  const size_t need = kv_elems * 2 * sizeof(short);  // Kb + Vt = 8 MB

  if (ws_size >= need) {
    short* kb = (short*)d_ws;
    short* vt = kb + kv_elems;
    prepack<<<dim3(1536), dim3(256), 0, stream>>>(k, v, kb, vt);
    attn_fwd<1><<<dim3(NB * (AQ / 16)), dim3(256), 0, stream>>>(q, k, v, m, kb, vt, o);
  } else {
    attn_fwd<0><<<dim3(NB * (AQ / 16)), dim3(256), 0, stream>>>(q, k, v, m, nullptr, nullptr, o);
  }
}

// Round 8
// 147.025 us; speedup vs baseline: 1.5397x; 1.5397x over previous
//
#include <hip/hip_runtime.h>

// Problem constants (reference: N=16, A=2048, B=2048, H=64)
#define NB 16
#define AQ 2048
#define BKV 2048
#define HD 64

#define L2E 1.44269504f
#define QSCALE 0.18033688f  // 0.125 * log2(e): softmax done in log2 domain
#define MBIAS -43000.0f     // additive mask bias (log2 units); exp2 -> exact 0

typedef float f32x4 __attribute__((ext_vector_type(4)));
typedef float f32x16 __attribute__((ext_vector_type(16)));
typedef short bf16x8 __attribute__((ext_vector_type(8)));
typedef int int4v __attribute__((ext_vector_type(4)));

__device__ __forceinline__ short f2bf(float f) {
  return __builtin_bit_cast(short, static_cast<__bf16>(f));
}
__device__ __forceinline__ unsigned pk2(float a, float b) {
  unsigned lo = (unsigned short)f2bf(a);
  unsigned hh = (unsigned short)f2bf(b);
  return lo | (hh << 16);
}

// -------------------- fused prepass (single launch, round-6 verified) --------
// blocks [0, 1024):   K f32 [n][b][h] -> Kb bf16 [n][b][h]
// blocks [1024, 1536): V f32 [n][b][h] -> Vt bf16 [n][h][b]  (64x64 LDS tile)
__global__ __launch_bounds__(256) void prepack(const float* __restrict__ K,
                                               const float* __restrict__ V,
                                               short* __restrict__ Kb,
                                               short* __restrict__ Vt) {
  if (blockIdx.x < 1024) {
    size_t base = ((size_t)blockIdx.x * 256 + threadIdx.x) * 8;
    f32x4 a = *(const f32x4*)(K + base);
    f32x4 b = *(const f32x4*)(K + base + 4);
    bf16x8 o;
#pragma unroll
    for (int i = 0; i < 4; ++i) {
      o[i] = f2bf(a[i]);
      o[i + 4] = f2bf(b[i]);
    }
    *(bf16x8*)(Kb + base) = o;
  } else {
    unsigned vb = blockIdx.x - 1024;
    int n = vb >> 5;
    int b0 = (vb & 31) * 64;
    int t = threadIdx.x;
    __shared__ short tile[64][68];
    int rb = t >> 4;
    int hc = (t & 15) * 4;
#pragma unroll
    for (int j = 0; j < 4; ++j) {
      int r = rb + 16 * j;
      f32x4 v = *(const f32x4*)(V + ((size_t)n * BKV + b0 + r) * HD + hc);
#pragma unroll
      for (int i = 0; i < 4; ++i) tile[r][hc + i] = f2bf(v[i]);
    }
    __syncthreads();
    int hr = t >> 2;
    int bb = (t & 3) * 16;
    bf16x8 o0, o1;
#pragma unroll
    for (int j = 0; j < 8; ++j) {
      o0[j] = tile[bb + j][hr];
      o1[j] = tile[bb + 8 + j][hr];
    }
    short* dst = Vt + ((size_t)n * HD + hr) * BKV + b0 + bb;
    *(bf16x8*)dst = o0;
    *(bf16x8*)(dst + 8) = o1;
  }
}

// ---------------------------- main flash kernel ------------------------------
// 32x32x16 MFMA, BOTH GEMMs swapped: S^T = mfma(K, Q), O^T = mfma(V^T, P^T).
// C/D col = lane&31 = q for both -> all softmax state lane-local in q:
// no shfl for acc rescale, no LDS for P, 1 shfl_xor(32) per reduce.
// Mask folded into QK^T C-init (additive -43000 bias, log2 domain).
// Block = 4 waves = 2 q-groups x 2 KV halves; each wave: 32 q x 1024 KV.
// Grid = N * A/64 = 512 blocks (2 blocks/CU, 2 waves/SIMD).
// __launch_bounds__(256, 2): VGPR cap 256 — NO spill (rounds 5/7: WRITE_SIZE
// 114-198 MB whenever acc spilled; keep WRITE_SIZE ~8 MB as the tripwire).
template <int PRE>
__global__ __launch_bounds__(256, 2) void attn_fwd(
    const float* __restrict__ Q, const float* __restrict__ K,
    const float* __restrict__ V, const int* __restrict__ M,
    const short* __restrict__ Kb, const short* __restrict__ Vt,
    float* __restrict__ O) {
  // bijective XCD swizzle: 512 blocks, 64 contiguous wgs per XCD (2 batches/XCD)
  unsigned orig = blockIdx.x;
  unsigned wg = (orig & 7u) * 64u + (orig >> 3);
  int n = (int)(wg >> 5);
  int q0 = (int)(wg & 31u) * 64;

  int w = threadIdx.x >> 6;  // wave 0..3
  int lane = threadIdx.x & 63;
  int hi = lane >> 5;        // half-wave id
  int li = lane & 31;
  int qg = w >> 1;           // q-group 0/1
  int half = w & 1;          // KV half 0/1
  int q0w = q0 + qg * 32;

  const float* Qn = Q + (size_t)n * AQ * HD;
  const float* Kn = K + (size_t)n * BKV * HD;
  const float* Vn = V + (size_t)n * BKV * HD;
  const short* Kbn = Kb + (size_t)n * BKV * HD;
  const short* Vtn = Vt + (size_t)n * HD * BKV;
  const int* Mn = M + (size_t)n * BKV;

  __shared__ __align__(16) float pacc[4][32][68];  // 34816 B partial O^T
  __shared__ float Ml[4][2][32];                   // m, l per wave per q

  // ---- Q fragments (B operand of swapped QK^T), log2-scale folded in.
  // B[k=h][j=q]: lane holds q = q0w + li, h = 16*ks + 8*hi + j (contiguous f32)
  bf16x8 qb[4];
#pragma unroll
  for (int ks = 0; ks < 4; ++ks) {
    const float* qp = Qn + (size_t)(q0w + li) * HD + 16 * ks + 8 * hi;
    f32x4 a = *(const f32x4*)qp;
    f32x4 b = *(const f32x4*)(qp + 4);
#pragma unroll
    for (int i = 0; i < 4; ++i) {
      qb[ks][i] = f2bf(a[i] * QSCALE);
      qb[ks][i + 4] = f2bf(b[i] * QSCALE);
    }
  }

  // acc0/acc1: O^T[h = 32*ht + crow(reg,hi)][q = li], crow = (r&3)+8*(r>>2)+4*hi
  f32x16 acc0 = {};
  f32x16 acc1 = {};
  float m_run = -1e30f;
  float l_run = 0.f;

  const int bstart = half * (BKV / 2);
  for (int b0 = bstart; b0 < bstart + (BKV / 2); b0 += 32) {
    // ---- mask -> C-init bias (row b_loc = 8j + 4hi + r)
    int4v mv[4];
#pragma unroll
    for (int j = 0; j < 4; ++j)
      mv[j] = *(const int4v*)(Mn + b0 + 8 * j + 4 * hi);
    f32x16 st;
#pragma unroll
    for (int j = 0; j < 4; ++j)
#pragma unroll
      for (int r = 0; r < 4; ++r) st[4 * j + r] = mv[j][r] ? MBIAS : 0.f;

    // ---- S^T = K.Q^T (+bias): st[reg] = S^T[b0 + crow(reg,hi)][q0w + li]
#pragma unroll
    for (int ks = 0; ks < 4; ++ks) {
      bf16x8 ka;
      if constexpr (PRE) {
        ka = *(const bf16x8*)(Kbn + (size_t)(b0 + li) * HD + 16 * ks + 8 * hi);
      } else {
        const float* kp = Kn + (size_t)(b0 + li) * HD + 16 * ks + 8 * hi;
        f32x4 k0 = *(const f32x4*)kp;
        f32x4 k1 = *(const f32x4*)(kp + 4);
#pragma unroll
        for (int i = 0; i < 4; ++i) {
          ka[i] = f2bf(k0[i]);
          ka[i + 4] = f2bf(k1[i]);
        }
      }
      st = __builtin_amdgcn_mfma_f32_32x32x16_bf16(ka, qb[ks], st, 0, 0, 0);
    }

    // ---- row max over 32 b (16 own regs + partner half via one shfl)
    float mt = st[0];
#pragma unroll
    for (int i = 1; i < 16; ++i) mt = fmaxf(mt, st[i]);
    mt = fmaxf(mt, __shfl_xor(mt, 32));
    float m_new = fmaxf(m_run, mt);
    float fac = exp2f(m_run - m_new);

    // ---- P = exp2(S - m) in place (log2 domain; masked -> exactly 0)
    float rs = 0.f;
#pragma unroll
    for (int i = 0; i < 16; ++i) {
      float e = exp2f(st[i] - m_new);
      st[i] = e;
      rs += e;
    }
    rs += __shfl_xor(rs, 32);
    l_run = l_run * fac + rs;
    m_run = m_new;

    // ---- rescale acc (fac is lane-local in q — no shfl!)
#pragma unroll
    for (int i = 0; i < 16; ++i) {
      acc0[i] *= fac;
      acc1[i] *= fac;
    }

    // ---- P^T B-operand: pack to bf16 words, redistribute across half-waves.
    // own words w8[j] = P[q][b-pair]; partner's via shfl_xor(32); select by hi.
    unsigned w8[8], sx[8];
#pragma unroll
    for (int j = 0; j < 8; ++j) w8[j] = pk2(st[2 * j], st[2 * j + 1]);
#pragma unroll
    for (int j = 0; j < 8; ++j) sx[j] = (unsigned)__shfl_xor((int)w8[j], 32);
    int4v p0 = {(int)(hi ? sx[2] : w8[0]), (int)(hi ? sx[3] : w8[1]),
                (int)(hi ? w8[2] : sx[0]), (int)(hi ? w8[3] : sx[1])};
    int4v p1 = {(int)(hi ? sx[6] : w8[4]), (int)(hi ? sx[7] : w8[5]),
                (int)(hi ? w8[6] : sx[4]), (int)(hi ? w8[7] : sx[5])};
    bf16x8 pb0 = __builtin_bit_cast(bf16x8, p0);
    bf16x8 pb1 = __builtin_bit_cast(bf16x8, p1);

    // ---- O^T += V^T . P^T : A[i=h][k=b] from Vt (contiguous bf16x8)
#pragma unroll
    for (int ht = 0; ht < 2; ++ht) {
      bf16x8 va0, va1;
      if constexpr (PRE) {
        const short* vp = Vtn + (size_t)(32 * ht + li) * BKV + b0 + 8 * hi;
        va0 = *(const bf16x8*)vp;
        va1 = *(const bf16x8*)(vp + 16);
      } else {
#pragma unroll
        for (int j = 0; j < 8; ++j) {
          va0[j] = f2bf(Vn[(size_t)(b0 + 8 * hi + j) * HD + 32 * ht + li]);
          va1[j] = f2bf(Vn[(size_t)(b0 + 16 + 8 * hi + j) * HD + 32 * ht + li]);
        }
      }
      if (ht == 0) {
        acc0 = __builtin_amdgcn_mfma_f32_32x32x16_bf16(va0, pb0, acc0, 0, 0, 0);
        acc0 = __builtin_amdgcn_mfma_f32_32x32x16_bf16(va1, pb1, acc0, 0, 0, 0);
      } else {
        acc1 = __builtin_amdgcn_mfma_f32_32x32x16_bf16(va0, pb0, acc1, 0, 0, 0);
        acc1 = __builtin_amdgcn_mfma_f32_32x32x16_bf16(va1, pb1, acc1, 0, 0, 0);
      }
    }
  }

  // ---- publish per-wave partials (m, l lane-local; acc^T scattered to [q][h])
  if (hi == 0) {
    Ml[w][0][li] = m_run;
    Ml[w][1][li] = l_run;
  }
#pragma unroll
  for (int reg = 0; reg < 16; ++reg) {
    int hrow = (reg & 3) + 8 * (reg >> 2) + 4 * hi;
    pacc[w][li][hrow] = acc0[reg];
    pacc[w][li][32 + hrow] = acc1[reg];
  }
  __syncthreads();

  // ---- merge the 2 KV halves per q-group; 256 threads cover 64 q x 4 h-quads
  {
    int tid = threadIdx.x;
    int q = tid >> 2;          // 0..63
    int qg2 = q >> 5;
    int ql = q & 31;
    int hb = (tid & 3) * 16;
    float ma = Ml[qg2 * 2 + 0][0][ql], mb = Ml[qg2 * 2 + 1][0][ql];
    float mmax = fmaxf(ma, mb);
    float fa = exp2f(ma - mmax), fb = exp2f(mb - mmax);
    float l = fa * Ml[qg2 * 2 + 0][1][ql] + fb * Ml[qg2 * 2 + 1][1][ql];
    float inv = 1.0f / l;
    float* op = O + ((size_t)n * AQ + q0 + q) * HD + hb;
#pragma unroll
    for (int t = 0; t < 4; ++t) {
      f32x4 xa = *(const f32x4*)&pacc[qg2 * 2 + 0][ql][hb + 4 * t];
      f32x4 xb = *(const f32x4*)&pacc[qg2 * 2 + 1][ql][hb + 4 * t];
      f32x4 res;
#pragma unroll
      for (int i = 0; i < 4; ++i) res[i] = (fa * xa[i] + fb * xb[i]) * inv;
      *(f32x4*)(op + 4 * t) = res;
    }
  }
}

extern "C" void kernel_launch(void* const* d_in, const int* in_sizes, int n_in,
                              void* d_out, int out_size, void* d_ws, size_t ws_size,
                              hipStream_t stream) {
  const float* q = (const float*)d_in[0];
  const float* k = (const float*)d_in[1];
  const float* v = (const float*)d_in[2];
  const int* m = (const int*)d_in[3];
  float* o = (float*)d_out;

  const size_t kv_elems = (size_t)NB * BKV * HD;     // 2,097,152
  const size_t need = kv_elems * 2 * sizeof(short);  // Kb + Vt = 8 MB

  if (ws_size >= need) {
    short* kb = (short*)d_ws;
    short* vt = kb + kv_elems;
    prepack<<<dim3(1536), dim3(256), 0, stream>>>(k, v, kb, vt);
    attn_fwd<1><<<dim3(NB * (AQ / 64)), dim3(256), 0, stream>>>(q, k, v, m, kb, vt, o);
  } else {
    attn_fwd<0><<<dim3(NB * (AQ / 64)), dim3(256), 0, stream>>>(q, k, v, m, nullptr, nullptr, o);
  }
}